// Round 10
// baseline (3676.406 us; speedup 1.0000x reference)
//
#include <hip/hip_runtime.h>
#include <hip/hip_bf16.h>
#include <math.h>

#define Bsz 1024
#define Hd  256
#define MAXT 72                  // max 16-row combo-uniform tiles/cell: (1024+9*15)/16 = 72
#define WTSTRIDE (768*512)       // one combo matrix, TRANSPOSED: [col(768)][k(512)] bf16

typedef short bf16x8 __attribute__((ext_vector_type(8)));   // 8 bf16 in 4 VGPRs
typedef float f32x4  __attribute__((ext_vector_type(4)));   // MFMA accumulator

// ---------- build 16 combined weight matrices, transposed + bf16-split ------
// (byte-identical to the absmax-0.0-validated rounds 8/9)
__global__ __launch_bounds__(256)
void build_wc(const float* __restrict__ W1, const float* __restrict__ W2,
              const float* __restrict__ Wm,
              __hip_bfloat16* __restrict__ Wht, __hip_bfloat16* __restrict__ Wlt)
{
    size_t idx = (size_t)blockIdx.x * 256 + threadIdx.x;   // < 16*768*512
    int k = (int)(idx & 511);
    size_t rem = idx >> 9;
    int col = (int)(rem % 768);
    int c = (int)(rem / 768);
    int a = c >> 2, b = c & 3;
    float v;
    if (col < 256) {
        v = ((a < 3) ? W1[(size_t)a * 512 * 256 + k * 256 + col] : 0.f)
          + ((b < 3) ? W1[(size_t)(3 + b) * 512 * 256 + k * 256 + col] : 0.f);
    } else if (col < 512) {
        int cc = col - 256;
        v = ((a < 3) ? W2[(size_t)a * 512 * 256 + k * 256 + cc] : 0.f)
          + ((b < 3) ? W2[(size_t)(3 + b) * 512 * 256 + k * 256 + cc] : 0.f);
    } else {
        v = Wm[(size_t)k * 256 + (col - 512)];
    }
    __hip_bfloat16 vh = __float2bfloat16(v);
    __hip_bfloat16 vl = __float2bfloat16(v - __bfloat162float(vh));
    Wht[idx] = vh;
    Wlt[idx] = vl;
}

// ---------- bucketize: combo-uniform 16-row tiles ---------------------------
// perm16[cell][tile*16+j] = sample index or -1 (pad); tiletab16[cell][tile] = combo or -1
__global__ __launch_bounds__(256)
void bucketize16(const int* __restrict__ samples, int* __restrict__ perm,
                 int* __restrict__ tiletab)
{
    const int cell = blockIdx.x;         // 0..63 snake order
    const int t = threadIdx.x;
    const int ny = cell >> 3, ixs = cell & 7;
    const int nx  = (ny & 1) ? (7 - ixs) : ixs;
    const int dx  = (ny & 1) ? 1 : -1;
    const int nxn = nx + dx;
    const bool hasX = (nxn >= 0) && (nxn < 8);
    const bool hasY = (ny > 0);
    const int sx_off = nxn * 8 + ny;
    const int sy_off = nx * 8 + ny - 1;

    __shared__ int hist[16], cursor[16];
    int* pcell = perm + (size_t)cell * (MAXT * 16);
    for (int i = t; i < MAXT * 16; i += 256) pcell[i] = -1;
    if (t < 16) hist[t] = 0;
    __syncthreads();

    int myc[4];
#pragma unroll
    for (int q = 0; q < 4; q++) {
        int l = t * 4 + q;
        int a = hasX ? samples[l * 64 + sx_off] : 3;
        int b = hasY ? samples[l * 64 + sy_off] : 3;
        myc[q] = a * 4 + b;
        atomicAdd(&hist[myc[q]], 1);
    }
    __syncthreads();

    if (t == 0) {
        int row = 0, ns = 0;
        for (int c = 0; c < 16; c++) {
            cursor[c] = row;
            int nt = (hist[c] + 15) >> 4;
            for (int k = 0; k < nt; k++) tiletab[cell * MAXT + ns++] = c;
            row += nt * 16;
        }
        for (; ns < MAXT; ns++) tiletab[cell * MAXT + ns] = -1;
    }
    __syncthreads();

#pragma unroll
    for (int q = 0; q < 4; q++) {
        int l = t * 4 + q;
        int pos = atomicAdd(&cursor[myc[q]], 1);
        pcell[pos] = l;
    }
}

// ---------------- fused per-cell kernel: GEMM + GRU + logprob ---------------
// grid: MAXT blocks x 1024 thr (16 waves). Block = one 16-row combo-uniform tile.
// Wave w owns col-triple {w*16.., 256+w*16.., 512+w*16..}: after 16 k-steps it
// holds complete pre1/pre2/merge for 16 rows x 16 cols in regs -> GRU in-register.
// 3-term bf16-split MFMA (validated layout: A row=lane&15, B col=lane&15,
// k=8*(lane>>4); D col=lane&15, row=4*(lane>>4)+reg).
__global__ __launch_bounds__(1024)
void fused_cell(const __hip_bfloat16* __restrict__ Hxh, const __hip_bfloat16* __restrict__ Hxl,
                const __hip_bfloat16* __restrict__ Hyh, const __hip_bfloat16* __restrict__ Hyl,
                const __hip_bfloat16* __restrict__ Wht, const __hip_bfloat16* __restrict__ Wlt,
                const float* __restrict__ b1, const float* __restrict__ b2,
                const float* __restrict__ Wl1, const float* __restrict__ bl1,
                const float* __restrict__ Wl2, const float* __restrict__ bl2,
                const int* __restrict__ perm16, const int* __restrict__ tiletab16,
                const int* __restrict__ samples,
                __hip_bfloat16* __restrict__ Houth, __hip_bfloat16* __restrict__ Houtl,
                float* __restrict__ acc, float* __restrict__ out,
                int cell, int s_off, int kcell, int ksb, int kse)
{
    const int combo = tiletab16[cell * MAXT + blockIdx.x];
    if (combo < 0) return;
    const int* pr = perm16 + ((size_t)cell * MAXT + blockIdx.x) * 16;

    const int t  = threadIdx.x;
    const int w  = t >> 6;               // wave 0..15 = col-triple index
    const int l  = t & 63;
    const int lr = l & 15;
    const int lg = l >> 4;

    const int myrow = pr[lr];            // A-operand row for this lane
    const int col   = w * 16 + lr;       // h-col owned by this lane (B col)

    f32x4 ac0 = {0.f,0.f,0.f,0.f};       // pre1 partial (cols 0..255)
    f32x4 ac1 = {0.f,0.f,0.f,0.f};       // pre2 partial (cols 256..511)
    f32x4 ac2 = {0.f,0.f,0.f,0.f};       // merge partial (cols 512..767)

    const __hip_bfloat16* B0h = Wht + (size_t)combo * WTSTRIDE + (size_t)col * 512;
    const __hip_bfloat16* B0l = Wlt + (size_t)combo * WTSTRIDE + (size_t)col * 512;
    const __hip_bfloat16* B1h = B0h + (size_t)256 * 512;
    const __hip_bfloat16* B1l = B0l + (size_t)256 * 512;
    const __hip_bfloat16* B2h = B0h + (size_t)512 * 512;
    const __hip_bfloat16* B2l = B0l + (size_t)512 * 512;

    for (int ks = ksb; ks < kse; ks++) {
        const __hip_bfloat16* Ah_ = (ks < 8) ? Hxh : Hyh;
        const __hip_bfloat16* Al_ = (ks < 8) ? Hxl : Hyl;
        const int koff = ((ks & 7) * 32) + lg * 8;   // k within the 256-wide half
        bf16x8 ah = (myrow >= 0) ? *(const bf16x8*)(Ah_ + (size_t)myrow * Hd + koff) : (bf16x8)0;
        bf16x8 al = (myrow >= 0) ? *(const bf16x8*)(Al_ + (size_t)myrow * Hd + koff) : (bf16x8)0;
        const int kw = ks * 32 + lg * 8;             // k within the 512-deep Wt
        bf16x8 b0h = *(const bf16x8*)(B0h + kw);
        bf16x8 b0l = *(const bf16x8*)(B0l + kw);
        bf16x8 b1h = *(const bf16x8*)(B1h + kw);
        bf16x8 b1l = *(const bf16x8*)(B1l + kw);
        bf16x8 b2h = *(const bf16x8*)(B2h + kw);
        bf16x8 b2l = *(const bf16x8*)(B2l + kw);

        ac0 = __builtin_amdgcn_mfma_f32_16x16x32_bf16(ah, b0h, ac0, 0, 0, 0);
        ac0 = __builtin_amdgcn_mfma_f32_16x16x32_bf16(ah, b0l, ac0, 0, 0, 0);
        ac0 = __builtin_amdgcn_mfma_f32_16x16x32_bf16(al, b0h, ac0, 0, 0, 0);
        ac1 = __builtin_amdgcn_mfma_f32_16x16x32_bf16(ah, b1h, ac1, 0, 0, 0);
        ac1 = __builtin_amdgcn_mfma_f32_16x16x32_bf16(ah, b1l, ac1, 0, 0, 0);
        ac1 = __builtin_amdgcn_mfma_f32_16x16x32_bf16(al, b1h, ac1, 0, 0, 0);
        ac2 = __builtin_amdgcn_mfma_f32_16x16x32_bf16(ah, b2h, ac2, 0, 0, 0);
        ac2 = __builtin_amdgcn_mfma_f32_16x16x32_bf16(ah, b2l, ac2, 0, 0, 0);
        ac2 = __builtin_amdgcn_mfma_f32_16x16x32_bf16(al, b2h, ac2, 0, 0, 0);
    }

    // ---- in-register GRU combine; lane covers rows 4lg+reg, col=col ----
    const float bb1 = b1[col], bb2 = b2[col];
    float hv[4];
#pragma unroll
    for (int reg = 0; reg < 4; reg++) {
        int r = pr[4 * lg + reg];
        float pre1 = ac0[reg] + bb1;
        float pre2 = ac1[reg] + bb2;
        float mg   = ac2[reg];
        float th = tanhf(pre1);
        float u  = 1.0f / (1.0f + expf(-pre2));
        float h  = u * th + (1.0f - u) * mg;
        hv[reg] = h;
        if (r >= 0) {
            __hip_bfloat16 hh = __float2bfloat16(h);
            __hip_bfloat16 hl = __float2bfloat16(h - __bfloat162float(hh));
            Houth[(size_t)r * Hd + col] = hh;
            Houtl[(size_t)r * Hd + col] = hl;
        }
    }

    // ---- readout partials: vr[reg][i] = h * Wl[col][i]; reduce over 16 cols ----
    float w1c0 = Wl1[col * 3 + 0], w1c1 = Wl1[col * 3 + 1], w1c2 = Wl1[col * 3 + 2];
    float w2c0 = Wl2[col * 3 + 0], w2c1 = Wl2[col * 3 + 1], w2c2 = Wl2[col * 3 + 2];
    float vr[4][6];
#pragma unroll
    for (int reg = 0; reg < 4; reg++) {
        vr[reg][0] = hv[reg] * w1c0; vr[reg][1] = hv[reg] * w1c1; vr[reg][2] = hv[reg] * w1c2;
        vr[reg][3] = hv[reg] * w2c0; vr[reg][4] = hv[reg] * w2c1; vr[reg][5] = hv[reg] * w2c2;
    }
#pragma unroll
    for (int m = 1; m < 16; m <<= 1)
#pragma unroll
        for (int reg = 0; reg < 4; reg++)
#pragma unroll
            for (int i = 0; i < 6; i++)
                vr[reg][i] += __shfl_xor(vr[reg][i], m, 16);

    __shared__ float red[16][16][6];     // [wave][row][i]
    __shared__ float redS[16][6];
    if (lr == 0) {
#pragma unroll
        for (int reg = 0; reg < 4; reg++)
#pragma unroll
            for (int i = 0; i < 6; i++)
                red[w][4 * lg + reg][i] = vr[reg][i];
    }
    __syncthreads();

    if (t < 96) {
        int row = t / 6, i = t - row * 6;
        float s = 0.f;
#pragma unroll
        for (int ww = 0; ww < 16; ww++) s += red[ww][row][i];
        redS[row][i] = s;
    }
    __syncthreads();

    // ---- scalar logprob update: one thread per real row ----
    if (t < 16) {
        int r = pr[t];
        if (r >= 0) {
            float p1[3] = {redS[t][0], redS[t][1], redS[t][2]};
            float p2[3] = {redS[t][3], redS[t][4], redS[t][5]};
            float la, lp, nu, nd;
            if (kcell == 0) { la = 0.f; lp = 0.f; nu = 0.f; nd = 0.f; }
            else {
                la = acc[r];           lp = acc[Bsz + r];
                nu = acc[2 * Bsz + r]; nd = acc[3 * Bsz + r];
            }
            float z0 = p1[0] + bl1[0], z1 = p1[1] + bl1[1], z2 = p1[2] + bl1[2];
            float zm = fmaxf(z0, fmaxf(z1, z2));
            float e0 = expf(z0 - zm), e1 = expf(z1 - zm), e2 = expf(z2 - zm);
            float es = e0 + e1 + e2;
            float mh = (16.0f - ((float)kcell - nu - nd) > 0.0f) ? 1.0f : 0.0f;
            float md = (24.0f - nd > 0.0f) ? 1.0f : 0.0f;
            float mu = (24.0f - nu > 0.0f) ? 1.0f : 0.0f;
            float a0 = (e0 / es) * mh, a1 = (e1 / es) * md, a2 = (e2 / es) * mu;
            float asum = fmaxf(a0 + a1 + a2, 1e-30f);
            int sv = samples[r * 64 + s_off];
            float av = ((sv == 0) ? a0 : (sv == 1) ? a1 : a2) / asum;
            float q  = p2[sv] + bl2[sv];
            float ph = 3.14159265358979323846f * (q / (1.0f + fabsf(q)));
            la += logf(fmaxf(av, 1e-12f));
            lp += ph;
            nu += (sv == 2) ? 1.0f : 0.0f;
            nd += (sv == 1) ? 1.0f : 0.0f;
            acc[r] = la; acc[Bsz + r] = lp;
            acc[2 * Bsz + r] = nu; acc[3 * Bsz + r] = nd;
            if (kcell == 63) {
                out[r]       = 0.5f * la;
                out[Bsz + r] = lp;
            }
        }
    }
}

// ---------------------------------------------------------------------------
extern "C" void kernel_launch(void* const* d_in, const int* in_sizes, int n_in,
                              void* d_out, int out_size, void* d_ws, size_t ws_size,
                              hipStream_t stream)
{
    const int*   samples = (const int*)  d_in[0];
    const float* W1  = (const float*)d_in[1];
    const float* b1  = (const float*)d_in[2];
    const float* W2  = (const float*)d_in[3];
    const float* b2  = (const float*)d_in[4];
    const float* Wm  = (const float*)d_in[5];
    const float* Wl1 = (const float*)d_in[6];
    const float* bl1 = (const float*)d_in[7];
    const float* Wl2 = (const float*)d_in[8];
    const float* bl2 = (const float*)d_in[9];

    float* ws = (float*)d_ws;
    float* acc = ws;                                          // 4*B f32
    __hip_bfloat16* Hh  = (__hip_bfloat16*)(acc + 4 * Bsz);   // 16 slots (8 col x 2 parity)
    __hip_bfloat16* Hl  = Hh + (size_t)16 * Bsz * Hd;
    __hip_bfloat16* Wht = Hl + (size_t)16 * Bsz * Hd;         // 16*768*512 bf16
    __hip_bfloat16* Wlt = Wht + (size_t)16 * WTSTRIDE;
    int* perm16   = (int*)(Wlt + (size_t)16 * WTSTRIDE);      // 64*MAXT*16
    int* tiletab16 = perm16 + (size_t)64 * MAXT * 16;         // 64*MAXT
    float* out = (float*)d_out;

    build_wc<<<dim3(16 * 768 * 512 / 256), dim3(256), 0, stream>>>(W1, W2, Wm, Wht, Wlt);
    bucketize16<<<dim3(64), dim3(256), 0, stream>>>(samples, perm16, tiletab16);

    int kcell = 0;
    for (int ny = 0; ny < 8; ny++) {
        const int x0  = (ny % 2 == 0) ? 0 : 7;
        const int dxs = (ny % 2 == 0) ? 1 : -1;
        const int dx  = (ny % 2 == 0) ? -1 : 1;
        for (int ix = 0; ix < 8; ix++) {
            const int nx  = x0 + ix * dxs;
            const int nxn = nx + dx;
            const bool hasX = (nxn >= 0 && nxn < 8);
            const bool hasY = (ny > 0);
            const int p   = ny & 1;
            // double-buffered H slots: write slot (nx,p); hx from (nxn,p); hy from (nx,1-p)
            const size_t slotW  = ((size_t)nx * 2 + p) * Bsz * Hd;
            const size_t slotX  = ((size_t)(hasX ? nxn : 0) * 2 + p) * Bsz * Hd;
            const size_t slotY  = ((size_t)nx * 2 + (1 - p)) * Bsz * Hd;
            const int ksb = hasX ? 0 : 8;
            const int kse = hasY ? 16 : 8;

            fused_cell<<<dim3(MAXT), dim3(1024), 0, stream>>>(
                Hh + slotX, Hl + slotX, Hh + slotY, Hl + slotY,
                Wht, Wlt, b1, b2, Wl1, bl1, Wl2, bl2,
                perm16, tiletab16, samples,
                Hh + slotW, Hl + slotW, acc, out,
                kcell, nx * 8 + ny, kcell, ksb, kse);
            kcell++;
        }
    }
}

// Round 13
// 1752.839 us; speedup vs baseline: 2.0974x; 2.0974x over previous
//
#include <hip/hip_runtime.h>
#include <hip/hip_bf16.h>
#include <math.h>

#define Bsz 1024
#define Hd  256
#define NCOL 3328                // 13 slabs x 256 cols
#define NCOLP 3344               // +16 pad cols (over-compute guard)

typedef short bf16x8 __attribute__((ext_vector_type(8)));   // 8 bf16 in 4 VGPRs
typedef float f32x4  __attribute__((ext_vector_type(4)));   // MFMA accumulator

// ---------- build 13 transposed bf16-split weight slabs ---------------------
// Wt[col][k], col = v*256+cc: v<6 -> W1[v][k][cc]; v<12 -> W2[v-6]; v=12 -> Wm
__global__ __launch_bounds__(256)
void build_wc13(const float* __restrict__ W1, const float* __restrict__ W2,
                const float* __restrict__ Wm,
                __hip_bfloat16* __restrict__ Wht, __hip_bfloat16* __restrict__ Wlt)
{
    size_t idx = (size_t)blockIdx.x * 256 + threadIdx.x;   // < 3328*512
    int k   = (int)(idx & 511);
    int col = (int)(idx >> 9);
    int v   = col >> 8;
    int cc  = col & 255;
    float val;
    if (v < 6)       val = W1[(size_t)v * 512 * 256 + k * 256 + cc];
    else if (v < 12) val = W2[(size_t)(v - 6) * 512 * 256 + k * 256 + cc];
    else             val = Wm[(size_t)k * 256 + cc];
    __hip_bfloat16 vh = __float2bfloat16(val);
    __hip_bfloat16 vl = __float2bfloat16(val - __bfloat162float(vh));
    Wht[idx] = vh;
    Wlt[idx] = vl;
}

// ---------------- dense-13 MFMA GEMM, XCD-pinned B --------------------------
// Gall[l, 0:3328] = st[l] @ Wt ; st = [hx | hy] (absent half skipped via phases)
// grid: 256 blocks x 512 thr. bid&7 = XCD group (416 cols), (bid>>3)&7 = rowtile
// of 128, bid>>6 = colsub {7,7,6,6} frags. Wave w = rows wrow..wrow+15 x 112 cols.
// B staged per 64k-slab in LDS (coalesced, +8 short pad). 3-term bf16 split.
__global__ __launch_bounds__(512)
void gemm13(const __hip_bfloat16* __restrict__ Hxh, const __hip_bfloat16* __restrict__ Hxl,
            const __hip_bfloat16* __restrict__ Hyh, const __hip_bfloat16* __restrict__ Hyl,
            const __hip_bfloat16* __restrict__ Wht, const __hip_bfloat16* __restrict__ Wlt,
            float* __restrict__ Gall, int pbeg, int pend)
{
    const int suboff[4] = {0, 7, 14, 20};
    const int subcnt[4] = {7, 7, 6, 6};
    const int bid    = blockIdx.x;
    const int xcd    = bid & 7;
    const int rowtile= (bid >> 3) & 7;
    const int colsub = bid >> 6;
    const int fragbase = xcd * 26 + suboff[colsub];
    const int nfrag    = subcnt[colsub];
    const int colbase  = fragbase * 16;
    const int rowbase  = rowtile * 128;

    const int t  = threadIdx.x;
    const int w  = t >> 6;               // wave 0..7
    const int l  = t & 63;
    const int lr = l & 15;
    const int lg = l >> 4;
    const int wrow = rowbase + w * 16;   // wave's 16-row base
    const int arow = wrow + lr;          // this lane's A row

    __shared__ __align__(16) short BhS[112 * 72];   // 64k-slab, 8-short pad
    __shared__ __align__(16) short BlS[112 * 72];

    f32x4 acc[7];
#pragma unroll
    for (int f = 0; f < 7; f++) acc[f] = (f32x4){0.f, 0.f, 0.f, 0.f};

    for (int p = pbeg; p < pend; p++) {              // phases of 64 k
        __syncthreads();                             // prev compute done
        for (int i = t; i < 896; i += 512) {         // stage 112 cols x 8 quads
            int c = i >> 3, q = i & 7;
            size_t src = (size_t)(colbase + c) * 512 + p * 64 + q * 8;
            *(uint4*)&BhS[c * 72 + q * 8] = *(const uint4*)&Wht[src];
            *(uint4*)&BlS[c * 72 + q * 8] = *(const uint4*)&Wlt[src];
        }
        __syncthreads();

#pragma unroll
        for (int ks2 = 0; ks2 < 2; ks2++) {          // two 32k steps per slab
            const int ks = p * 2 + ks2;              // absolute step 0..15
            const __hip_bfloat16* Ah_ = (ks < 8) ? Hxh : Hyh;
            const __hip_bfloat16* Al_ = (ks < 8) ? Hxl : Hyl;
            const int koff = ((ks & 7) * 32) + lg * 8;
            bf16x8 ah = *(const bf16x8*)(Ah_ + (size_t)arow * Hd + koff);
            bf16x8 al = *(const bf16x8*)(Al_ + (size_t)arow * Hd + koff);

            const int kloc = ks2 * 32 + lg * 8;
            bf16x8 bh[7], bl[7];
#pragma unroll
            for (int f = 0; f < 7; f++) {
                bh[f] = *(const bf16x8*)&BhS[(f * 16 + lr) * 72 + kloc];
                bl[f] = *(const bf16x8*)&BlS[(f * 16 + lr) * 72 + kloc];
            }
#pragma unroll
            for (int f = 0; f < 7; f++)
                acc[f] = __builtin_amdgcn_mfma_f32_16x16x32_bf16(ah, bh[f], acc[f], 0, 0, 0);
#pragma unroll
            for (int f = 0; f < 7; f++)
                acc[f] = __builtin_amdgcn_mfma_f32_16x16x32_bf16(ah, bl[f], acc[f], 0, 0, 0);
#pragma unroll
            for (int f = 0; f < 7; f++)
                acc[f] = __builtin_amdgcn_mfma_f32_16x16x32_bf16(al, bh[f], acc[f], 0, 0, 0);
        }
    }

    // D: col = lane&15, row = 4*(lane>>4)+reg (validated layout)
#pragma unroll
    for (int f = 0; f < 7; f++) {
        if (f < nfrag) {
            const int col = colbase + f * 16 + lr;
#pragma unroll
            for (int reg = 0; reg < 4; reg++) {
                const int row = wrow + 4 * lg + reg;
                Gall[(size_t)row * NCOL + col] = acc[f][reg];
            }
        }
    }
}

// ------- fused combine (GRU) + log-prob update (R7-validated structure) -----
// Gall slabs: pre1 = b1 + g[ix] + g[3+iy]; pre2 = b2 + g[6+ix] + g[9+iy]; mg = g[12]
__global__ __launch_bounds__(256)
void combine13(const float* __restrict__ Gall, const int* __restrict__ samples,
               const float* __restrict__ b1, const float* __restrict__ b2,
               const float* __restrict__ Wl1, const float* __restrict__ bl1,
               const float* __restrict__ Wl2, const float* __restrict__ bl2,
               __hip_bfloat16* __restrict__ houth, __hip_bfloat16* __restrict__ houtl,
               float* __restrict__ acc, float* __restrict__ out,
               int sx_off, int sy_off, int s_off, int kcell)
{
    const int l = blockIdx.x;
    const int k = threadIdx.x;
    const float* g = Gall + (size_t)l * NCOL;

    float pre1 = b1[k], pre2 = b2[k];
    float mg = g[12 * 256 + k];
    if (sx_off >= 0) {
        int ix = samples[l * 64 + sx_off];
        pre1 += g[ix * 256 + k];
        pre2 += g[(6 + ix) * 256 + k];
    }
    if (sy_off >= 0) {
        int iy = samples[l * 64 + sy_off];
        pre1 += g[(3 + iy) * 256 + k];
        pre2 += g[(9 + iy) * 256 + k];
    }
    float ht = tanhf(pre1);
    float u  = 1.0f / (1.0f + expf(-pre2));
    float h  = u * ht + (1.0f - u) * mg;
    __hip_bfloat16 hh = __float2bfloat16(h);
    __hip_bfloat16 hl = __float2bfloat16(h - __bfloat162float(hh));
    houth[(size_t)l * Hd + k] = hh;
    houtl[(size_t)l * Hd + k] = hl;

    float v[6];
    v[0] = h * Wl1[k * 3 + 0];
    v[1] = h * Wl1[k * 3 + 1];
    v[2] = h * Wl1[k * 3 + 2];
    v[3] = h * Wl2[k * 3 + 0];
    v[4] = h * Wl2[k * 3 + 1];
    v[5] = h * Wl2[k * 3 + 2];
#pragma unroll
    for (int m = 1; m < 64; m <<= 1)
#pragma unroll
        for (int i = 0; i < 6; i++) v[i] += __shfl_xor(v[i], m);

    __shared__ float red[4][6];
    if ((k & 63) == 0) {
#pragma unroll
        for (int i = 0; i < 6; i++) red[k >> 6][i] = v[i];
    }
    __syncthreads();

    if (k == 0) {
        float p1[3], p2[3];
#pragma unroll
        for (int i = 0; i < 3; i++) {
            p1[i] = red[0][i]     + red[1][i]     + red[2][i]     + red[3][i];
            p2[i] = red[0][3 + i] + red[1][3 + i] + red[2][3 + i] + red[3][3 + i];
        }
        float la, lp, nu, nd;
        if (kcell == 0) { la = 0.f; lp = 0.f; nu = 0.f; nd = 0.f; }
        else {
            la = acc[l];           lp = acc[Bsz + l];
            nu = acc[2 * Bsz + l]; nd = acc[3 * Bsz + l];
        }
        float z0 = p1[0] + bl1[0], z1 = p1[1] + bl1[1], z2 = p1[2] + bl1[2];
        float zm = fmaxf(z0, fmaxf(z1, z2));
        float e0 = expf(z0 - zm), e1 = expf(z1 - zm), e2 = expf(z2 - zm);
        float es = e0 + e1 + e2;
        float mh = (16.0f - ((float)kcell - nu - nd) > 0.0f) ? 1.0f : 0.0f;
        float md = (24.0f - nd > 0.0f) ? 1.0f : 0.0f;
        float mu = (24.0f - nu > 0.0f) ? 1.0f : 0.0f;
        float a0 = (e0 / es) * mh, a1 = (e1 / es) * md, a2 = (e2 / es) * mu;
        float asum = fmaxf(a0 + a1 + a2, 1e-30f);
        int sv = samples[l * 64 + s_off];
        float av = ((sv == 0) ? a0 : (sv == 1) ? a1 : a2) / asum;
        float q  = p2[sv] + bl2[sv];
        float ph = 3.14159265358979323846f * (q / (1.0f + fabsf(q)));
        la += logf(fmaxf(av, 1e-12f));
        lp += ph;
        nu += (sv == 2) ? 1.0f : 0.0f;
        nd += (sv == 1) ? 1.0f : 0.0f;
        acc[l] = la; acc[Bsz + l] = lp;
        acc[2 * Bsz + l] = nu; acc[3 * Bsz + l] = nd;
        if (kcell == 63) {
            out[l]       = 0.5f * la;
            out[Bsz + l] = lp;
        }
    }
}

// ---------------------------------------------------------------------------
extern "C" void kernel_launch(void* const* d_in, const int* in_sizes, int n_in,
                              void* d_out, int out_size, void* d_ws, size_t ws_size,
                              hipStream_t stream)
{
    const int*   samples = (const int*)  d_in[0];
    const float* W1  = (const float*)d_in[1];
    const float* b1  = (const float*)d_in[2];
    const float* W2  = (const float*)d_in[3];
    const float* b2  = (const float*)d_in[4];
    const float* Wm  = (const float*)d_in[5];
    const float* Wl1 = (const float*)d_in[6];
    const float* bl1 = (const float*)d_in[7];
    const float* Wl2 = (const float*)d_in[8];
    const float* bl2 = (const float*)d_in[9];

    float* ws = (float*)d_ws;
    float* Gall = ws;                                        // 1024*3328 f32
    float* acc  = Gall + (size_t)Bsz * NCOL;                 // 4*B f32
    __hip_bfloat16* Hh  = (__hip_bfloat16*)(acc + 4 * Bsz);  // 8 col-slots
    __hip_bfloat16* Hl  = Hh + (size_t)8 * Bsz * Hd;
    __hip_bfloat16* Wht = Hl + (size_t)8 * Bsz * Hd;         // NCOLP*512 bf16
    __hip_bfloat16* Wlt = Wht + (size_t)NCOLP * 512;
    float* out = (float*)d_out;

    build_wc13<<<dim3(NCOL * 512 / 256), dim3(256), 0, stream>>>(W1, W2, Wm, Wht, Wlt);

    int kcell = 0;
    for (int ny = 0; ny < 8; ny++) {
        const int x0  = (ny % 2 == 0) ? 0 : 7;
        const int dxs = (ny % 2 == 0) ? 1 : -1;
        const int dx  = (ny % 2 == 0) ? -1 : 1;
        for (int ix = 0; ix < 8; ix++) {
            const int nx  = x0 + ix * dxs;
            const int nxn = nx + dx;
            const bool hasX = (nxn >= 0 && nxn < 8);
            const bool hasY = (ny > 0);
            const int pbeg = hasX ? 0 : 4;
            const int pend = hasY ? 8 : 4;
            const size_t slotX = (size_t)(hasX ? nxn : 0) * Bsz * Hd;
            const size_t slotY = (size_t)nx * Bsz * Hd;

            gemm13<<<dim3(256), dim3(512), 0, stream>>>(
                Hh + slotX, Hl + slotX, Hh + slotY, Hl + slotY,
                Wht, Wlt, Gall, pbeg, pend);

            const int sx_off = hasX ? (nxn * 8 + ny)       : -1;
            const int sy_off = hasY ? (nx  * 8 + (ny - 1)) : -1;
            combine13<<<dim3(Bsz), dim3(256), 0, stream>>>(
                Gall, samples, b1, b2, Wl1, bl1, Wl2, bl2,
                Hh + slotY, Hl + slotY, acc, out,
                sx_off, sy_off, nx * 8 + ny, kcell);
            kcell++;
        }
    }
}